// Round 1
// baseline (1073.694 us; speedup 1.0000x reference)
//
#include <hip/hip_runtime.h>

#define DEVI static __device__ __forceinline__

typedef short s16x8 __attribute__((ext_vector_type(8)));
typedef float f32x4 __attribute__((ext_vector_type(4)));
typedef unsigned short u16;

constexpr int BATCH = 32;
constexpr int NTOK  = 577;
constexpr int DIMC  = 768;
constexpr int NH    = 12;
constexpr int HD    = 64;
constexpr int NQKV  = 3 * DIMC;        // 2304
constexpr int MROWS = BATCH * NTOK;    // 18464
constexpr int NPAD  = 608;             // 19*32 = 38*16 padded token count
constexpr int NN2   = NTOK * NTOK;     // 332929
constexpr int NKT   = 38;              // 16-wide col tiles covering 608
constexpr int PSTR  = 648;             // P row stride (pad +8 -> conflict-free b128)
constexpr float SCALE = 0.125f;        // 64^-0.5
constexpr float LOG2E = 1.44269504088896f;

// ---------- bf16 helpers (RNE) ----------
DEVI u16 f2b(float x) {
  unsigned u = __float_as_uint(x);
  u += 0x7fffu + ((u >> 16) & 1u);
  return (u16)(u >> 16);
}
DEVI float b2f(u16 h) { return __uint_as_float((unsigned)h << 16); }

DEVI void async16(void* lds, const void* g) {
  __builtin_amdgcn_global_load_lds((const __attribute__((address_space(1))) void*)g,
                                   (__attribute__((address_space(3))) void*)lds,
                                   16, 0, 0);
}
DEVI f32x4 mfma16(s16x8 a, s16x8 b, f32x4 c) {
  return __builtin_amdgcn_mfma_f32_16x16x32_bf16(a, b, c, 0, 0, 0);
}

// ---------- prep kernels ----------
// split fp32 -> bf16 hi/lo, same layout (vectorized x4)
__global__ __launch_bounds__(256) void split_plain(const float4* __restrict__ in,
                                                   ushort4* __restrict__ hi,
                                                   ushort4* __restrict__ lo, int n4) {
  int t = blockIdx.x * 256 + threadIdx.x;
  if (t >= n4) return;
  float4 v = in[t];
  ushort4 H, L;
  H.x = f2b(v.x); L.x = f2b(v.x - b2f(H.x));
  H.y = f2b(v.y); L.y = f2b(v.y - b2f(H.y));
  H.z = f2b(v.z); L.z = f2b(v.z - b2f(H.z));
  H.w = f2b(v.w); L.w = f2b(v.w - b2f(H.w));
  hi[t] = H; lo[t] = L;
}

// w[K][Nc] (fp32) -> thi/tlo [Nc][K] (bf16), transposed for [N][K] B-operand
__global__ __launch_bounds__(256) void split_transpose(const float* __restrict__ w,
                                                       u16* __restrict__ thi,
                                                       u16* __restrict__ tlo,
                                                       int K, int Nc) {
  int t = blockIdx.x * 256 + threadIdx.x;
  if (t >= K * Nc) return;
  int n = t / K, k = t - n * K;
  float v = w[(size_t)k * Nc + n];
  u16 h = f2b(v);
  thi[t] = h;
  tlo[t] = f2b(v - b2f(h));
}

// bias_table[2210][12] gathered by rel_index[577*577] -> bx[12][577][577] fp32
__global__ __launch_bounds__(256) void bias_expand(const float* __restrict__ tab,
                                                   const int* __restrict__ rel,
                                                   float* __restrict__ out) {
  int t = blockIdx.x * 256 + threadIdx.x;
  if (t >= NH * NN2) return;
  int h = t / NN2, qk = t - h * NN2;
  out[t] = tab[(size_t)rel[qk] * NH + h];
}

// ---------- split-bf16 GEMM (m97 structure, 128x128 tile, BK=32) ----------
// C[m][n] = sum_k A[m][k]*B[n][k] via 3 passes: Ahi*Bhi + Ahi*Blo + Alo*Bhi
// MODE 0: proj epilogue (fp32 out + bias). MODE 1: qkv scatter epilogue.
template <int MODE>
__global__ __launch_bounds__(256) void gemm_split3(
    const u16* __restrict__ Ahi, const u16* __restrict__ Alo,
    const u16* __restrict__ Bhi, const u16* __restrict__ Blo,
    int M, int Nn, int K, int ntn,
    float* __restrict__ outF, const float* __restrict__ pbias,
    u16* __restrict__ qb, u16* __restrict__ kb, u16* __restrict__ vt) {
  __shared__ __align__(16) u16 At[128 * 32];
  __shared__ __align__(16) u16 Bt[128 * 32];
  const int tid = threadIdx.x;
  const int lane = tid & 63, wv = tid >> 6;
  const int g = lane >> 4, c = lane & 15;
  const int mt = blockIdx.x / ntn, ntb = blockIdx.x % ntn;
  const int m0 = mt * 128, n0 = ntb * 128;
  const int wr = wv >> 1, wc = wv & 1;

  f32x4 acc[4][4] = {};

  // staging: chunk = 16B; LDS linear [row][slot], global k-chunk = slot ^ ((row>>1)&3)
  const int ch0 = tid, ch1 = 256 + tid;
  const int r0 = ch0 >> 2, gk0 = (((ch0 & 3) ^ ((r0 >> 1) & 3)) * 8);
  const int r1 = ch1 >> 2, gk1 = (((ch1 & 3) ^ ((r1 >> 1) & 3)) * 8);
  const int ar0 = (m0 + r0 < M) ? (m0 + r0) : (M - 1);
  const int ar1 = (m0 + r1 < M) ? (m0 + r1) : (M - 1);
  const int br0 = n0 + r0, br1 = n0 + r1;

  for (int term = 0; term < 3; ++term) {
    const u16* As = (term == 2) ? Alo : Ahi;
    const u16* Bs = (term == 1) ? Blo : Bhi;
    const u16* a0p = As + (size_t)ar0 * K + gk0;
    const u16* a1p = As + (size_t)ar1 * K + gk1;
    const u16* b0p = Bs + (size_t)br0 * K + gk0;
    const u16* b1p = Bs + (size_t)br1 * K + gk1;
    for (int kk = 0; kk < K; kk += 32) {
      async16(&At[ch0 * 8], a0p + kk);
      async16(&At[ch1 * 8], a1p + kk);
      async16(&Bt[ch0 * 8], b0p + kk);
      async16(&Bt[ch1 * 8], b1p + kk);
      __syncthreads();
      s16x8 af[4], bfr[4];
#pragma unroll
      for (int mi = 0; mi < 4; ++mi) {
        int row = wr * 64 + mi * 16 + c;
        int sl = g ^ ((row >> 1) & 3);
        af[mi] = *(const s16x8*)&At[row * 32 + sl * 8];
      }
#pragma unroll
      for (int ni = 0; ni < 4; ++ni) {
        int row = wc * 64 + ni * 16 + c;
        int sl = g ^ ((row >> 1) & 3);
        bfr[ni] = *(const s16x8*)&Bt[row * 32 + sl * 8];
      }
#pragma unroll
      for (int mi = 0; mi < 4; ++mi)
#pragma unroll
        for (int ni = 0; ni < 4; ++ni)
          acc[mi][ni] = mfma16(af[mi], bfr[ni], acc[mi][ni]);
      __syncthreads();
    }
  }

  // epilogue: C/D frag: col = lane&15, row = (lane>>4)*4 + reg
#pragma unroll
  for (int mi = 0; mi < 4; ++mi) {
#pragma unroll
    for (int ni = 0; ni < 4; ++ni) {
#pragma unroll
      for (int r = 0; r < 4; ++r) {
        int row = m0 + wr * 64 + mi * 16 + g * 4 + r;
        int col = n0 + wc * 64 + ni * 16 + c;
        if (row < M) {
          float v = acc[mi][ni][r];
          if constexpr (MODE == 0) {
            outF[(size_t)row * Nn + col] = v + pbias[col];
          } else {
            int b = row / NTOK, tok = row - b * NTOK;
            int s = col / DIMC, rr = col - s * DIMC;
            int h = rr >> 6, d = rr & 63;
            size_t bh = (size_t)b * NH + h;
            if (s == 2) {
              vt[(bh * HD + d) * NPAD + tok] = f2b(v);  // V transposed [bh][d][tok]
            } else {
              u16* dst = (s == 0) ? qb : kb;            // [bh][tok][d]
              dst[(bh * NPAD + tok) * HD + d] = f2b(v);
            }
          }
        }
      }
    }
  }
}

// ---------- attention: 1 block = (b,h, 32-row q tile); 4 waves split col-tiles ----------
__global__ __launch_bounds__(256) void attn_kernel(
    const u16* __restrict__ qb, const u16* __restrict__ kb, const u16* __restrict__ vt,
    const float* __restrict__ bx, u16* __restrict__ aohi, u16* __restrict__ aolo) {
  __shared__ __align__(16) u16 P[32 * PSTR];
  __shared__ float redm[4][32];
  __shared__ float reds[4][32];
  const int tid = threadIdx.x, lane = tid & 63, wv = tid >> 6;
  const int g = lane >> 4, c = lane & 15;
  const int blk = blockIdx.x;
  const int qt = blk % 19;
  const int bh = blk / 19;
  const int h = bh % NH;
  const int b = bh / NH;
  const int q0 = qt * 32;

  // Q fragments: A-layout row=lane&15, k contiguous 8 at (lane>>4)*8
  s16x8 qf[2][2];
#pragma unroll
  for (int mf = 0; mf < 2; ++mf)
#pragma unroll
    for (int ks = 0; ks < 2; ++ks)
      qf[mf][ks] = *(const s16x8*)(qb + ((size_t)bh * NPAD + q0 + mf * 16 + c) * HD + ks * 32 + g * 8);

  // S tiles in registers: wave wv owns tiles t = wv + 4j, j = 0..9 (static unroll)
  f32x4 sacc[10][2];
#pragma unroll
  for (int j = 0; j < 10; ++j) {
    int t = wv + 4 * j;
    f32x4 z = {0.f, 0.f, 0.f, 0.f};
    sacc[j][0] = z; sacc[j][1] = z;
    if (t < NKT) {
#pragma unroll
      for (int ks = 0; ks < 2; ++ks) {
        s16x8 kf = *(const s16x8*)(kb + ((size_t)bh * NPAD + t * 16 + c) * HD + ks * 32 + g * 8);
        sacc[j][0] = mfma16(qf[0][ks], kf, sacc[j][0]);
        sacc[j][1] = mfma16(qf[1][ks], kf, sacc[j][1]);
      }
    }
  }

  // scale + rel-pos bias + mask; running row max (lane-local)
  float rmax[2][4];
#pragma unroll
  for (int mf = 0; mf < 2; ++mf)
#pragma unroll
    for (int r = 0; r < 4; ++r) rmax[mf][r] = -1e30f;
  const float* bb = bx + (size_t)h * NN2;
#pragma unroll
  for (int j = 0; j < 10; ++j) {
    int t = wv + 4 * j;
    if (t < NKT) {
      int kcol = t * 16 + c;
#pragma unroll
      for (int mf = 0; mf < 2; ++mf) {
        int qrow = q0 + mf * 16 + g * 4;
#pragma unroll
        for (int r = 0; r < 4; ++r) {
          float sv;
          if (qrow + r < NTOK && kcol < NTOK)
            sv = sacc[j][mf][r] * SCALE + bb[(size_t)(qrow + r) * NTOK + kcol];
          else
            sv = -1e30f;
          sacc[j][mf][r] = sv;
          rmax[mf][r] = fmaxf(rmax[mf][r], sv);
        }
      }
    }
  }
  // butterfly max over the 16 lanes sharing g
#pragma unroll
  for (int d = 1; d < 16; d <<= 1)
#pragma unroll
    for (int mf = 0; mf < 2; ++mf)
#pragma unroll
      for (int r = 0; r < 4; ++r)
        rmax[mf][r] = fmaxf(rmax[mf][r], __shfl_xor(rmax[mf][r], d));
  if (c == 0) {
#pragma unroll
    for (int mf = 0; mf < 2; ++mf)
#pragma unroll
      for (int r = 0; r < 4; ++r) redm[wv][mf * 16 + g * 4 + r] = rmax[mf][r];
  }
  __syncthreads();
  float fmx[2][4];
#pragma unroll
  for (int mf = 0; mf < 2; ++mf)
#pragma unroll
    for (int r = 0; r < 4; ++r) {
      int row = mf * 16 + g * 4 + r;
      fmx[mf][r] = fmaxf(fmaxf(redm[0][row], redm[1][row]), fmaxf(redm[2][row], redm[3][row]));
    }

  // exp, write P (bf16) to LDS, accumulate row sum
  float rsum[2][4] = {};
#pragma unroll
  for (int j = 0; j < 10; ++j) {
    int t = wv + 4 * j;
    if (t < NKT) {
#pragma unroll
      for (int mf = 0; mf < 2; ++mf)
#pragma unroll
        for (int r = 0; r < 4; ++r) {
          float p = exp2f((sacc[j][mf][r] - fmx[mf][r]) * LOG2E);
          rsum[mf][r] += p;
          P[(mf * 16 + g * 4 + r) * PSTR + t * 16 + c] = f2b(p);
        }
    }
  }
#pragma unroll
  for (int d = 1; d < 16; d <<= 1)
#pragma unroll
    for (int mf = 0; mf < 2; ++mf)
#pragma unroll
      for (int r = 0; r < 4; ++r) rsum[mf][r] += __shfl_xor(rsum[mf][r], d);
  if (c == 0) {
#pragma unroll
    for (int mf = 0; mf < 2; ++mf)
#pragma unroll
      for (int r = 0; r < 4; ++r) reds[wv][mf * 16 + g * 4 + r] = rsum[mf][r];
  }
  __syncthreads();  // P fully written + sums available
  float fsm[2][4];
#pragma unroll
  for (int mf = 0; mf < 2; ++mf)
#pragma unroll
    for (int r = 0; r < 4; ++r) {
      int row = mf * 16 + g * 4 + r;
      fsm[mf][r] = (reds[0][row] + reds[1][row]) + (reds[2][row] + reds[3][row]);
    }

  // PV: out[32][64], wave wv owns d-cols [wv*16, wv*16+16)
  f32x4 oacc[2] = {};
  for (int ks = 0; ks < 19; ++ks) {
    s16x8 pf0 = *(const s16x8*)&P[(size_t)c * PSTR + ks * 32 + g * 8];
    s16x8 pf1 = *(const s16x8*)&P[(size_t)(16 + c) * PSTR + ks * 32 + g * 8];
    s16x8 vf = *(const s16x8*)(vt + ((size_t)bh * HD + wv * 16 + c) * NPAD + ks * 32 + g * 8);
    oacc[0] = mfma16(pf0, vf, oacc[0]);
    oacc[1] = mfma16(pf1, vf, oacc[1]);
  }

  // normalize + hi/lo split write for proj GEMM A-operand
#pragma unroll
  for (int mf = 0; mf < 2; ++mf) {
#pragma unroll
    for (int r = 0; r < 4; ++r) {
      int tok = q0 + mf * 16 + g * 4 + r;
      if (tok < NTOK) {
        float v = oacc[mf][r] / fsm[mf][r];
        size_t idx = ((size_t)b * NTOK + tok) * DIMC + h * HD + wv * 16 + c;
        u16 hi = f2b(v);
        aohi[idx] = hi;
        aolo[idx] = f2b(v - b2f(hi));
      }
    }
  }
}

// ---------- launch ----------
extern "C" void kernel_launch(void* const* d_in, const int* in_sizes, int n_in,
                              void* d_out, int out_size, void* d_ws, size_t ws_size,
                              hipStream_t stream) {
  const float* x      = (const float*)d_in[0];
  const float* qkv_w  = (const float*)d_in[1];
  const float* btab   = (const float*)d_in[2];
  const float* proj_w = (const float*)d_in[3];
  const float* proj_b = (const float*)d_in[4];
  const int*   rel    = (const int*)d_in[5];
  float* out = (float*)d_out;

  // workspace layout (~172 MB total)
  char* ws = (char*)d_ws;
  size_t off = 0;
  auto alloc = [&](size_t bytes) {
    void* p = ws + off;
    off += (bytes + 255) & ~(size_t)255;
    return p;
  };
  constexpr size_t SZ_QKVB = (size_t)BATCH * NH * NPAD * HD * 2;  // 29.9 MB each
  u16* qb = (u16*)alloc(SZ_QKVB);
  u16* kb = (u16*)alloc(SZ_QKVB);
  u16* vt = (u16*)alloc(SZ_QKVB);
  float* bx = (float*)alloc((size_t)NH * NN2 * 4);                // 16 MB
  u16* wth = (u16*)alloc((size_t)NQKV * DIMC * 2);
  u16* wtl = (u16*)alloc((size_t)NQKV * DIMC * 2);
  u16* w2h = (u16*)alloc((size_t)DIMC * DIMC * 2);
  u16* w2l = (u16*)alloc((size_t)DIMC * DIMC * 2);
  u16* xhi = (u16*)alloc((size_t)MROWS * DIMC * 2);               // aliased: attn out hi
  u16* xlo = (u16*)alloc((size_t)MROWS * DIMC * 2);               // aliased: attn out lo
  u16* aohi = xhi;  // x-split dead after QKV GEMM -> reuse
  u16* aolo = xlo;

  dim3 blk(256);
  {
    int n4 = MROWS * DIMC / 4;
    split_plain<<<(n4 + 255) / 256, blk, 0, stream>>>((const float4*)x, (ushort4*)xhi, (ushort4*)xlo, n4);
  }
  {
    int n = DIMC * NQKV;
    split_transpose<<<(n + 255) / 256, blk, 0, stream>>>(qkv_w, wth, wtl, DIMC, NQKV);
  }
  {
    int n = DIMC * DIMC;
    split_transpose<<<(n + 255) / 256, blk, 0, stream>>>(proj_w, w2h, w2l, DIMC, DIMC);
  }
  {
    int n = NH * NN2;
    bias_expand<<<(n + 255) / 256, blk, 0, stream>>>(btab, rel, bx);
  }
  {
    int mt = (MROWS + 127) / 128;  // 145
    int nt = NQKV / 128;           // 18
    gemm_split3<1><<<mt * nt, blk, 0, stream>>>(xhi, xlo, wth, wtl, MROWS, NQKV, DIMC, nt,
                                                nullptr, nullptr, qb, kb, vt);
  }
  attn_kernel<<<BATCH * NH * 19, blk, 0, stream>>>(qb, kb, vt, bx, aohi, aolo);
  {
    int mt = (MROWS + 127) / 128;  // 145
    int nt = DIMC / 128;           // 6
    gemm_split3<0><<<mt * nt, blk, 0, stream>>>(aohi, aolo, w2h, w2l, MROWS, DIMC, DIMC, nt,
                                                out, proj_b, nullptr, nullptr, nullptr);
  }
}

// Round 5
// 730.709 us; speedup vs baseline: 1.4694x; 1.4694x over previous
//
#include <hip/hip_runtime.h>

#define DEVI static __device__ __forceinline__

typedef short s16x8 __attribute__((ext_vector_type(8)));
typedef float f32x4 __attribute__((ext_vector_type(4)));
typedef unsigned short u16;

constexpr int BATCH = 32;
constexpr int NTOK  = 577;
constexpr int DIMC  = 768;
constexpr int NH    = 12;
constexpr int HD    = 64;
constexpr int NQKV  = 3 * DIMC;        // 2304
constexpr int MROWS = BATCH * NTOK;    // 18464
constexpr int NPAD  = 608;             // 19*32 padded token count
constexpr int NN2   = NTOK * NTOK;
constexpr int NKT   = 38;              // 16-wide col tiles covering 608
constexpr float SCALE = 0.125f;        // 64^-0.5
constexpr float LOG2E = 1.44269504088896f;

// ---------- bf16 helpers (RNE) ----------
DEVI u16 f2b(float x) {
  unsigned u = __float_as_uint(x);
  u += 0x7fffu + ((u >> 16) & 1u);
  return (u16)(u >> 16);
}
DEVI float b2f(u16 h) { return __uint_as_float((unsigned)h << 16); }

DEVI void async16(void* lds, const void* g) {
  __builtin_amdgcn_global_load_lds((const __attribute__((address_space(1))) void*)g,
                                   (__attribute__((address_space(3))) void*)lds,
                                   16, 0, 0);
}
DEVI f32x4 mfma16(s16x8 a, s16x8 b, f32x4 c) {
  return __builtin_amdgcn_mfma_f32_16x16x32_bf16(a, b, c, 0, 0, 0);
}

// ---------- prep kernels ----------
__global__ __launch_bounds__(256) void split_plain(const float4* __restrict__ in,
                                                   ushort4* __restrict__ hi,
                                                   ushort4* __restrict__ lo, int n4) {
  int t = blockIdx.x * 256 + threadIdx.x;
  if (t >= n4) return;
  float4 v = in[t];
  ushort4 H, L;
  H.x = f2b(v.x); L.x = f2b(v.x - b2f(H.x));
  H.y = f2b(v.y); L.y = f2b(v.y - b2f(H.y));
  H.z = f2b(v.z); L.z = f2b(v.z - b2f(H.z));
  H.w = f2b(v.w); L.w = f2b(v.w - b2f(H.w));
  hi[t] = H; lo[t] = L;
}

__global__ __launch_bounds__(256) void split_transpose(const float* __restrict__ w,
                                                       u16* __restrict__ thi,
                                                       u16* __restrict__ tlo,
                                                       int K, int Nc) {
  int t = blockIdx.x * 256 + threadIdx.x;
  if (t >= K * Nc) return;
  int n = t / K, k = t - n * K;
  float v = w[(size_t)k * Nc + n];
  u16 h = f2b(v);
  thi[t] = h;
  tlo[t] = f2b(v - b2f(h));
}

// bias -> bf16 [12][577][608], cols >=577 zeroed
__global__ __launch_bounds__(256) void bias_expand_bf16(const float* __restrict__ tab,
                                                        const int* __restrict__ rel,
                                                        u16* __restrict__ out) {
  int t = blockIdx.x * 256 + threadIdx.x;
  if (t >= NH * NTOK * NPAD) return;
  int h = t / (NTOK * NPAD);
  int r = t - h * (NTOK * NPAD);
  int q = r / NPAD, kc = r - q * NPAD;
  float v = (kc < NTOK) ? tab[(size_t)rel[q * NTOK + kc] * NH + h] : 0.f;
  out[t] = f2b(v);
}

// ---------- fused 3-term split-bf16 GEMM (128x128 tile, BK=32) ----------
// C = Ahi*Bhi + Ahi*Blo + Alo*Bhi per K-chunk (single staging, single barrier pair)
template <int MODE>
__global__ __launch_bounds__(256) void gemm_split3(
    const u16* __restrict__ Ahi, const u16* __restrict__ Alo,
    const u16* __restrict__ Bhi, const u16* __restrict__ Blo,
    int M, int Nn, int K, int ntn,
    float* __restrict__ outF, const float* __restrict__ pbias,
    u16* __restrict__ qb, u16* __restrict__ kb, u16* __restrict__ vt) {
  __shared__ __align__(16) u16 Ah[128 * 32];
  __shared__ __align__(16) u16 Al[128 * 32];
  __shared__ __align__(16) u16 Bh[128 * 32];
  __shared__ __align__(16) u16 Bl[128 * 32];
  const int tid = threadIdx.x;
  const int lane = tid & 63, wv = tid >> 6;
  const int g = lane >> 4, c = lane & 15;
  const int mt = blockIdx.x / ntn, ntb = blockIdx.x % ntn;
  const int m0 = mt * 128, n0 = ntb * 128;
  const int wr = wv >> 1, wc = wv & 1;

  f32x4 acc[4][4] = {};

  // staging: 16B chunks, LDS linear, global k-chunk = slot ^ ((row>>1)&3)
  const int ch0 = tid, ch1 = 256 + tid;
  const int r0 = ch0 >> 2, gk0 = (((ch0 & 3) ^ ((r0 >> 1) & 3)) * 8);
  const int r1 = ch1 >> 2, gk1 = (((ch1 & 3) ^ ((r1 >> 1) & 3)) * 8);
  const int ar0 = (m0 + r0 < M) ? (m0 + r0) : (M - 1);
  const int ar1 = (m0 + r1 < M) ? (m0 + r1) : (M - 1);
  const int br0 = n0 + r0, br1 = n0 + r1;

  const u16* ah0 = Ahi + (size_t)ar0 * K + gk0;
  const u16* ah1 = Ahi + (size_t)ar1 * K + gk1;
  const u16* al0 = Alo + (size_t)ar0 * K + gk0;
  const u16* al1 = Alo + (size_t)ar1 * K + gk1;
  const u16* bh0 = Bhi + (size_t)br0 * K + gk0;
  const u16* bh1 = Bhi + (size_t)br1 * K + gk1;
  const u16* bl0 = Blo + (size_t)br0 * K + gk0;
  const u16* bl1 = Blo + (size_t)br1 * K + gk1;

  for (int kk = 0; kk < K; kk += 32) {
    async16(&Ah[ch0 * 8], ah0 + kk);
    async16(&Ah[ch1 * 8], ah1 + kk);
    async16(&Al[ch0 * 8], al0 + kk);
    async16(&Al[ch1 * 8], al1 + kk);
    async16(&Bh[ch0 * 8], bh0 + kk);
    async16(&Bh[ch1 * 8], bh1 + kk);
    async16(&Bl[ch0 * 8], bl0 + kk);
    async16(&Bl[ch1 * 8], bl1 + kk);
    __syncthreads();
    s16x8 afh[4], afl[4];
#pragma unroll
    for (int mi = 0; mi < 4; ++mi) {
      int row = wr * 64 + mi * 16 + c;
      int sl = g ^ ((row >> 1) & 3);
      afh[mi] = *(const s16x8*)&Ah[row * 32 + sl * 8];
      afl[mi] = *(const s16x8*)&Al[row * 32 + sl * 8];
    }
#pragma unroll
    for (int ni = 0; ni < 4; ++ni) {
      int row = wc * 64 + ni * 16 + c;
      int sl = g ^ ((row >> 1) & 3);
      s16x8 bfh = *(const s16x8*)&Bh[row * 32 + sl * 8];
      s16x8 bfl = *(const s16x8*)&Bl[row * 32 + sl * 8];
#pragma unroll
      for (int mi = 0; mi < 4; ++mi) {
        f32x4 t0 = mfma16(afh[mi], bfl, acc[mi][ni]);
        t0 = mfma16(afl[mi], bfh, t0);
        acc[mi][ni] = mfma16(afh[mi], bfh, t0);
      }
    }
    __syncthreads();
  }

  // epilogue: C/D frag: col = lane&15, row = (lane>>4)*4 + reg
#pragma unroll
  for (int mi = 0; mi < 4; ++mi) {
#pragma unroll
    for (int ni = 0; ni < 4; ++ni) {
#pragma unroll
      for (int r = 0; r < 4; ++r) {
        int row = m0 + wr * 64 + mi * 16 + g * 4 + r;
        int col = n0 + wc * 64 + ni * 16 + c;
        if (row < M) {
          float v = acc[mi][ni][r];
          if constexpr (MODE == 0) {
            outF[(size_t)row * Nn + col] = v + pbias[col];
          } else {
            int b = row / NTOK, tok = row - b * NTOK;
            int s = col / DIMC, rr = col - s * DIMC;
            int h = rr >> 6, d = rr & 63;
            size_t bh = (size_t)b * NH + h;
            if (s == 2) {
              vt[(bh * HD + d) * NPAD + tok] = f2b(v);  // V transposed
            } else {
              u16* dst = (s == 0) ? qb : kb;
              dst[(bh * NPAD + tok) * HD + d] = f2b(v);
            }
          }
        }
      }
    }
  }
}

// ---------- attention ----------
// LDS slab [32][608] bf16 holds bias (prefetched, overlapped with QK^T), then P.
// Swizzle: u16 idx = row*608 + (col ^ ((row&3)<<3)); applied to source prefetch,
// bias reads, P writes, P reads.
__global__ __launch_bounds__(256) void attn_kernel(
    const u16* __restrict__ qb, const u16* __restrict__ kb, const u16* __restrict__ vt,
    const u16* __restrict__ bxh, u16* __restrict__ aohi, u16* __restrict__ aolo) {
  __shared__ __align__(16) u16 SLAB[32 * NPAD];   // 38912 B
  __shared__ float redm[4][32];
  __shared__ float reds[4][32];
  const int tid = threadIdx.x, lane = tid & 63, wv = tid >> 6;
  const int g = lane >> 4, c = lane & 15;
  const int blk = blockIdx.x;
  const int qt = blk % 19;
  const int bh = blk / 19;
  const int h = bh % NH;
  const int b = bh / NH;
  const int q0 = qt * 32;

  // --- issue bias slab prefetch (32 rows x 1216B = 2432 chunks), pre-swizzled src ---
  {
    const char* bsrc = (const char*)(bxh + (size_t)(h * NTOK + q0) * NPAD);
#pragma unroll
    for (int t = 0; t < 10; ++t) {
      int ch = t * 256 + tid;
      if (ch < 2432) {
        int row = ch / 76, off = ch - row * 76;
        int sch = row * 76 + (off ^ (row & 3));
        async16(&SLAB[ch * 8], bsrc + (size_t)sch * 16);
      }
    }
  }

  // --- Q fragments ---
  s16x8 qf[2][2];
#pragma unroll
  for (int mf = 0; mf < 2; ++mf)
#pragma unroll
    for (int ks = 0; ks < 2; ++ks)
      qf[mf][ks] = *(const s16x8*)(qb + ((size_t)bh * NPAD + q0 + mf * 16 + c) * HD + ks * 32 + g * 8);

  // --- QK^T: wave wv owns tiles t = wv + 4j ---
  f32x4 sacc[10][2];
#pragma unroll
  for (int j = 0; j < 10; ++j) {
    int t = wv + 4 * j;
    f32x4 z = {0.f, 0.f, 0.f, 0.f};
    sacc[j][0] = z; sacc[j][1] = z;
    if (t < NKT) {
#pragma unroll
      for (int ks = 0; ks < 2; ++ks) {
        s16x8 kf = *(const s16x8*)(kb + ((size_t)bh * NPAD + t * 16 + c) * HD + ks * 32 + g * 8);
        sacc[j][0] = mfma16(qf[0][ks], kf, sacc[j][0]);
        sacc[j][1] = mfma16(qf[1][ks], kf, sacc[j][1]);
      }
    }
  }

  __syncthreads();  // bias slab resident (barrier drains global_load_lds)

  // --- scale + bias (LDS) + mask; row max ---
  float rmax[2][4];
#pragma unroll
  for (int mf = 0; mf < 2; ++mf)
#pragma unroll
    for (int r = 0; r < 4; ++r) rmax[mf][r] = -1e30f;
#pragma unroll
  for (int j = 0; j < 10; ++j) {
    int t = wv + 4 * j;
    if (t < NKT) {
      int kcol = t * 16 + c;
#pragma unroll
      for (int mf = 0; mf < 2; ++mf) {
#pragma unroll
        for (int r = 0; r < 4; ++r) {
          int lrow = mf * 16 + g * 4 + r;
          float bias = b2f(SLAB[lrow * NPAD + (kcol ^ ((lrow & 3) << 3))]);
          float sv;
          if (q0 + lrow < NTOK && kcol < NTOK)
            sv = sacc[j][mf][r] * SCALE + bias;
          else
            sv = -1e30f;
          sacc[j][mf][r] = sv;
          rmax[mf][r] = fmaxf(rmax[mf][r], sv);
        }
      }
    }
  }
#pragma unroll
  for (int d = 1; d < 16; d <<= 1)
#pragma unroll
    for (int mf = 0; mf < 2; ++mf)
#pragma unroll
      for (int r = 0; r < 4; ++r)
        rmax[mf][r] = fmaxf(rmax[mf][r], __shfl_xor(rmax[mf][r], d));
  if (c == 0) {
#pragma unroll
    for (int mf = 0; mf < 2; ++mf)
#pragma unroll
      for (int r = 0; r < 4; ++r) redm[wv][mf * 16 + g * 4 + r] = rmax[mf][r];
  }
  __syncthreads();  // separates all bias reads from P writes
  float fmx[2][4];
#pragma unroll
  for (int mf = 0; mf < 2; ++mf)
#pragma unroll
    for (int r = 0; r < 4; ++r) {
      int row = mf * 16 + g * 4 + r;
      fmx[mf][r] = fmaxf(fmaxf(redm[0][row], redm[1][row]), fmaxf(redm[2][row], redm[3][row]));
    }

  // --- exp -> P into SLAB (swizzled), row sums ---
  float rsum[2][4] = {};
#pragma unroll
  for (int j = 0; j < 10; ++j) {
    int t = wv + 4 * j;
    if (t < NKT) {
      int kcol = t * 16 + c;
#pragma unroll
      for (int mf = 0; mf < 2; ++mf)
#pragma unroll
        for (int r = 0; r < 4; ++r) {
          int lrow = mf * 16 + g * 4 + r;
          float p = exp2f((sacc[j][mf][r] - fmx[mf][r]) * LOG2E);
          rsum[mf][r] += p;
          SLAB[lrow * NPAD + (kcol ^ ((lrow & 3) << 3))] = f2b(p);
        }
    }
  }
#pragma unroll
  for (int d = 1; d < 16; d <<= 1)
#pragma unroll
    for (int mf = 0; mf < 2; ++mf)
#pragma unroll
      for (int r = 0; r < 4; ++r) rsum[mf][r] += __shfl_xor(rsum[mf][r], d);
  if (c == 0) {
#pragma unroll
    for (int mf = 0; mf < 2; ++mf)
#pragma unroll
      for (int r = 0; r < 4; ++r) reds[wv][mf * 16 + g * 4 + r] = rsum[mf][r];
  }
  __syncthreads();  // P written + sums available
  float fsm[2][4];
#pragma unroll
  for (int mf = 0; mf < 2; ++mf)
#pragma unroll
    for (int r = 0; r < 4; ++r) {
      int row = mf * 16 + g * 4 + r;
      fsm[mf][r] = (reds[0][row] + reds[1][row]) + (reds[2][row] + reds[3][row]);
    }

  // --- PV: wave wv owns d-cols [wv*16, wv*16+16) ---
  f32x4 oacc[2] = {};
  for (int ks = 0; ks < 19; ++ks) {
    int col = ks * 32 + g * 8;
    s16x8 pf0 = *(const s16x8*)&SLAB[c * NPAD + (col ^ ((c & 3) << 3))];
    s16x8 pf1 = *(const s16x8*)&SLAB[(16 + c) * NPAD + (col ^ ((c & 3) << 3))];
    s16x8 vf = *(const s16x8*)(vt + ((size_t)bh * HD + wv * 16 + c) * NPAD + col);
    oacc[0] = mfma16(pf0, vf, oacc[0]);
    oacc[1] = mfma16(pf1, vf, oacc[1]);
  }

  // --- normalize + hi/lo split write ---
#pragma unroll
  for (int mf = 0; mf < 2; ++mf) {
#pragma unroll
    for (int r = 0; r < 4; ++r) {
      int tok = q0 + mf * 16 + g * 4 + r;
      if (tok < NTOK) {
        float v = oacc[mf][r] / fsm[mf][r];
        size_t idx = ((size_t)b * NTOK + tok) * DIMC + h * HD + wv * 16 + c;
        u16 hi = f2b(v);
        aohi[idx] = hi;
        aolo[idx] = f2b(v - b2f(hi));
      }
    }
  }
}

// ---------- launch ----------
extern "C" void kernel_launch(void* const* d_in, const int* in_sizes, int n_in,
                              void* d_out, int out_size, void* d_ws, size_t ws_size,
                              hipStream_t stream) {
  const float* x      = (const float*)d_in[0];
  const float* qkv_w  = (const float*)d_in[1];
  const float* btab   = (const float*)d_in[2];
  const float* proj_w = (const float*)d_in[3];
  const float* proj_b = (const float*)d_in[4];
  const int*   rel    = (const int*)d_in[5];
  float* out = (float*)d_out;

  char* ws = (char*)d_ws;
  size_t off = 0;
  auto alloc = [&](size_t bytes) {
    void* p = ws + off;
    off += (bytes + 255) & ~(size_t)255;
    return p;
  };
  constexpr size_t SZ_QKVB = (size_t)BATCH * NH * NPAD * HD * 2;
  u16* qb = (u16*)alloc(SZ_QKVB);
  u16* kb = (u16*)alloc(SZ_QKVB);
  u16* vt = (u16*)alloc(SZ_QKVB);
  u16* bxh = (u16*)alloc(((size_t)NH * NTOK + 32) * NPAD * 2);  // +32-row pad for tail prefetch
  u16* wth = (u16*)alloc((size_t)NQKV * DIMC * 2);
  u16* wtl = (u16*)alloc((size_t)NQKV * DIMC * 2);
  u16* w2h = (u16*)alloc((size_t)DIMC * DIMC * 2);
  u16* w2l = (u16*)alloc((size_t)DIMC * DIMC * 2);
  u16* xhi = (u16*)alloc((size_t)MROWS * DIMC * 2);
  u16* xlo = (u16*)alloc((size_t)MROWS * DIMC * 2);
  u16* aohi = xhi;  // x-split dead after QKV GEMM -> reuse
  u16* aolo = xlo;

  dim3 blk(256);
  {
    int n4 = MROWS * DIMC / 4;
    split_plain<<<(n4 + 255) / 256, blk, 0, stream>>>((const float4*)x, (ushort4*)xhi, (ushort4*)xlo, n4);
  }
  {
    int n = DIMC * NQKV;
    split_transpose<<<(n + 255) / 256, blk, 0, stream>>>(qkv_w, wth, wtl, DIMC, NQKV);
  }
  {
    int n = DIMC * DIMC;
    split_transpose<<<(n + 255) / 256, blk, 0, stream>>>(proj_w, w2h, w2l, DIMC, DIMC);
  }
  {
    int n = NH * NTOK * NPAD;
    bias_expand_bf16<<<(n + 255) / 256, blk, 0, stream>>>(btab, rel, bxh);
  }
  {
    int mt = (MROWS + 127) / 128;  // 145
    int nt = NQKV / 128;           // 18
    gemm_split3<1><<<mt * nt, blk, 0, stream>>>(xhi, xlo, wth, wtl, MROWS, NQKV, DIMC, nt,
                                                nullptr, nullptr, qb, kb, vt);
  }
  attn_kernel<<<BATCH * NH * 19, blk, 0, stream>>>(qb, kb, vt, bxh, aohi, aolo);
  {
    int mt = (MROWS + 127) / 128;  // 145
    int nt = DIMC / 128;           // 6
    gemm_split3<0><<<mt * nt, blk, 0, stream>>>(aohi, aolo, w2h, w2l, MROWS, DIMC, DIMC, nt,
                                                out, proj_b, nullptr, nullptr, nullptr);
  }
}

// Round 6
// 715.881 us; speedup vs baseline: 1.4998x; 1.0207x over previous
//
#include <hip/hip_runtime.h>

#define DEVI static __device__ __forceinline__

typedef short s16x8 __attribute__((ext_vector_type(8)));
typedef float f32x4 __attribute__((ext_vector_type(4)));
typedef unsigned short u16;

constexpr int BATCH = 32;
constexpr int NTOK  = 577;
constexpr int DIMC  = 768;
constexpr int NH    = 12;
constexpr int HD    = 64;
constexpr int NQKV  = 3 * DIMC;        // 2304
constexpr int MROWS = BATCH * NTOK;    // 18464
constexpr int NPAD  = 608;             // 19*32 padded token count
constexpr int NKT   = 38;              // 16-wide col tiles covering 608
constexpr float SCALE = 0.125f;        // 64^-0.5
constexpr float LOG2E = 1.44269504088896f;

// ---------- bf16 helpers (RNE) ----------
DEVI u16 f2b(float x) {
  unsigned u = __float_as_uint(x);
  u += 0x7fffu + ((u >> 16) & 1u);
  return (u16)(u >> 16);
}
DEVI float b2f(u16 h) { return __uint_as_float((unsigned)h << 16); }

DEVI void async16(void* lds, const void* g) {
  __builtin_amdgcn_global_load_lds((const __attribute__((address_space(1))) void*)g,
                                   (__attribute__((address_space(3))) void*)lds,
                                   16, 0, 0);
}
DEVI f32x4 mfma16(s16x8 a, s16x8 b, f32x4 c) {
  return __builtin_amdgcn_mfma_f32_16x16x32_bf16(a, b, c, 0, 0, 0);
}

// ---------- prep kernels ----------
__global__ __launch_bounds__(256) void split_plain(const float4* __restrict__ in,
                                                   ushort4* __restrict__ hi,
                                                   ushort4* __restrict__ lo, int n4) {
  int t = blockIdx.x * 256 + threadIdx.x;
  if (t >= n4) return;
  float4 v = in[t];
  ushort4 H, L;
  H.x = f2b(v.x); L.x = f2b(v.x - b2f(H.x));
  H.y = f2b(v.y); L.y = f2b(v.y - b2f(H.y));
  H.z = f2b(v.z); L.z = f2b(v.z - b2f(H.z));
  H.w = f2b(v.w); L.w = f2b(v.w - b2f(H.w));
  hi[t] = H; lo[t] = L;
}

__global__ __launch_bounds__(256) void split_transpose(const float* __restrict__ w,
                                                       u16* __restrict__ thi,
                                                       u16* __restrict__ tlo,
                                                       int K, int Nc) {
  int t = blockIdx.x * 256 + threadIdx.x;
  if (t >= K * Nc) return;
  int n = t / K, k = t - n * K;
  float v = w[(size_t)k * Nc + n];
  u16 h = f2b(v);
  thi[t] = h;
  tlo[t] = f2b(v - b2f(h));
}

// bias -> fragment-ordered bf16 table [12][19][10][2][256][4]
// index: ((((h*19+qt)*10 + j)*2 + mf)*256 + tid)*4 + r
// value: bias[h][qt*32 + mf*16 + g*4 + r][(wv+4j)*16 + c], tid = wv*64+g*16+c
__global__ __launch_bounds__(256) void bias_expand_frag(const float* __restrict__ tab,
                                                        const int* __restrict__ rel,
                                                        u16* __restrict__ out) {
  int idx = blockIdx.x * 256 + threadIdx.x;           // one thread per 4-elem group
  if (idx >= NH * 19 * 10 * 2 * 256) return;
  int tid = idx & 255;
  int rest = idx >> 8;
  int mf = rest & 1; rest >>= 1;
  int j = rest % 10; rest /= 10;
  int qt = rest % 19;
  int h = rest / 19;
  int wv = tid >> 6, g = (tid >> 4) & 3, c = tid & 15;
  int t = wv + 4 * j;
  int kcol = t * 16 + c;
  u16 v4[4];
#pragma unroll
  for (int r = 0; r < 4; ++r) {
    int q = qt * 32 + mf * 16 + g * 4 + r;
    float v = 0.f;
    if (t < NKT && q < NTOK && kcol < NTOK)
      v = tab[(size_t)rel[q * NTOK + kcol] * NH + h];
    v4[r] = f2b(v);
  }
  *(ushort4*)(out + (size_t)idx * 4) = *(ushort4*)v4;
}

// ---------- fused 3-term split-bf16 GEMM, 2-phase double-buffered ----------
// C = Ahi*Bhi + Ahi*Blo + Alo*Bhi; stage next chunk BEFORE compute, 1 barrier/chunk.
template <int MODE>
__global__ __launch_bounds__(256, 2) void gemm_split3(
    const u16* __restrict__ Ahi, const u16* __restrict__ Alo,
    const u16* __restrict__ Bhi, const u16* __restrict__ Blo,
    int M, int Nn, int K, int ntn,
    float* __restrict__ outF, const float* __restrict__ pbias,
    u16* __restrict__ qb, u16* __restrict__ kb, u16* __restrict__ vt) {
  __shared__ __align__(16) u16 Ah[2][128 * 32];
  __shared__ __align__(16) u16 Al[2][128 * 32];
  __shared__ __align__(16) u16 Bh[2][128 * 32];
  __shared__ __align__(16) u16 Bl[2][128 * 32];
  const int tid = threadIdx.x;
  const int lane = tid & 63, wv = tid >> 6;
  const int g = lane >> 4, c = lane & 15;

  // bijective XCD swizzle (m204): co-locate same-mt blocks on one XCD
  const int nwg = gridDim.x, bid = blockIdx.x;
  const int qq = nwg >> 3, rr8 = nwg & 7, xc = bid & 7, ii = bid >> 3;
  const int swz = (xc < rr8 ? xc * (qq + 1) : rr8 * (qq + 1) + (xc - rr8) * qq) + ii;
  const int mt = swz / ntn, ntb = swz % ntn;
  const int m0 = mt * 128, n0 = ntb * 128;
  const int wr = wv >> 1, wc = wv & 1;

  f32x4 acc[4][4] = {};

  // staging: 16B chunks, LDS linear, global k-chunk = slot ^ ((row>>1)&3)
  const int ch0 = tid, ch1 = 256 + tid;
  const int r0 = ch0 >> 2, gk0 = (((ch0 & 3) ^ ((r0 >> 1) & 3)) * 8);
  const int r1 = ch1 >> 2, gk1 = (((ch1 & 3) ^ ((r1 >> 1) & 3)) * 8);
  const int ar0 = (m0 + r0 < M) ? (m0 + r0) : (M - 1);
  const int ar1 = (m0 + r1 < M) ? (m0 + r1) : (M - 1);
  const int br0 = n0 + r0, br1 = n0 + r1;

  const u16* ah0 = Ahi + (size_t)ar0 * K + gk0;
  const u16* ah1 = Ahi + (size_t)ar1 * K + gk1;
  const u16* al0 = Alo + (size_t)ar0 * K + gk0;
  const u16* al1 = Alo + (size_t)ar1 * K + gk1;
  const u16* bh0 = Bhi + (size_t)br0 * K + gk0;
  const u16* bh1 = Bhi + (size_t)br1 * K + gk1;
  const u16* bl0 = Blo + (size_t)br0 * K + gk0;
  const u16* bl1 = Blo + (size_t)br1 * K + gk1;

  auto STAGE = [&](int buf, int kk) {
    async16(&Ah[buf][ch0 * 8], ah0 + kk);
    async16(&Ah[buf][ch1 * 8], ah1 + kk);
    async16(&Al[buf][ch0 * 8], al0 + kk);
    async16(&Al[buf][ch1 * 8], al1 + kk);
    async16(&Bh[buf][ch0 * 8], bh0 + kk);
    async16(&Bh[buf][ch1 * 8], bh1 + kk);
    async16(&Bl[buf][ch0 * 8], bl0 + kk);
    async16(&Bl[buf][ch1 * 8], bl1 + kk);
  };
  auto COMPUTE = [&](int buf) {
    s16x8 afh[4], afl[4];
#pragma unroll
    for (int mi = 0; mi < 4; ++mi) {
      int row = wr * 64 + mi * 16 + c;
      int sl = g ^ ((row >> 1) & 3);
      afh[mi] = *(const s16x8*)&Ah[buf][row * 32 + sl * 8];
      afl[mi] = *(const s16x8*)&Al[buf][row * 32 + sl * 8];
    }
#pragma unroll
    for (int ni = 0; ni < 4; ++ni) {
      int row = wc * 64 + ni * 16 + c;
      int sl = g ^ ((row >> 1) & 3);
      s16x8 bfh = *(const s16x8*)&Bh[buf][row * 32 + sl * 8];
      s16x8 bfl = *(const s16x8*)&Bl[buf][row * 32 + sl * 8];
#pragma unroll
      for (int mi = 0; mi < 4; ++mi) {
        f32x4 t0 = mfma16(afh[mi], bfl, acc[mi][ni]);
        t0 = mfma16(afl[mi], bfh, t0);
        acc[mi][ni] = mfma16(afh[mi], bfh, t0);
      }
    }
  };

  STAGE(0, 0);
  __syncthreads();                 // drain prologue
  for (int kk = 0; kk < K; kk += 64) {
    if (kk + 32 < K) STAGE(1, kk + 32);   // loads fly during COMPUTE(0)
    COMPUTE(0);
    __syncthreads();               // drains buf1 loads; buf0 reads done
    if (kk + 64 < K) STAGE(0, kk + 64);   // loads fly during COMPUTE(1)
    COMPUTE(1);
    __syncthreads();               // drains buf0 loads; buf1 reads done
  }

  // epilogue: C/D frag: col = lane&15, row = (lane>>4)*4 + reg
#pragma unroll
  for (int mi = 0; mi < 4; ++mi) {
#pragma unroll
    for (int ni = 0; ni < 4; ++ni) {
#pragma unroll
      for (int r = 0; r < 4; ++r) {
        int row = m0 + wr * 64 + mi * 16 + g * 4 + r;
        int col = n0 + wc * 64 + ni * 16 + c;
        if (row < M) {
          float v = acc[mi][ni][r];
          if constexpr (MODE == 0) {
            outF[(size_t)row * Nn + col] = v + pbias[col];
          } else {
            int b = row / NTOK, tok = row - b * NTOK;
            int s = col / DIMC, rrx = col - s * DIMC;
            int h = rrx >> 6, d = rrx & 63;
            size_t bh = (size_t)b * NH + h;
            if (s == 2) {
              vt[(bh * HD + d) * NPAD + tok] = f2b(v);  // V transposed
            } else {
              u16* dst = (s == 0) ? qb : kb;
              dst[(bh * NPAD + tok) * HD + d] = f2b(v);
            }
          }
        }
      }
    }
  }
}

// ---------- attention ----------
// Bias from fragment-ordered global table (1 coalesced 8B load per (j,mf) per thread).
// LDS slab [32][608] bf16 holds P only. Swizzle col ^ ((row&3)<<3) on write+read.
__global__ __launch_bounds__(256, 4) void attn_kernel(
    const u16* __restrict__ qb, const u16* __restrict__ kb, const u16* __restrict__ vt,
    const u16* __restrict__ btf, u16* __restrict__ aohi, u16* __restrict__ aolo) {
  __shared__ __align__(16) u16 SLAB[32 * NPAD];   // 38912 B
  __shared__ float redm[4][32];
  __shared__ float reds[4][32];
  const int tid = threadIdx.x, lane = tid & 63, wv = tid >> 6;
  const int g = lane >> 4, c = lane & 15;
  const int blk = blockIdx.x;
  const int qt = blk % 19;
  const int bh = blk / 19;
  const int h = bh % NH;
  const int b = bh / NH;
  const int q0 = qt * 32;

  // --- Q fragments ---
  s16x8 qf[2][2];
#pragma unroll
  for (int mf = 0; mf < 2; ++mf)
#pragma unroll
    for (int ks = 0; ks < 2; ++ks)
      qf[mf][ks] = *(const s16x8*)(qb + ((size_t)bh * NPAD + q0 + mf * 16 + c) * HD + ks * 32 + g * 8);

  // --- QK^T: wave wv owns tiles t = wv + 4j ---
  f32x4 sacc[10][2];
#pragma unroll
  for (int j = 0; j < 10; ++j) {
    int t = wv + 4 * j;
    f32x4 z = {0.f, 0.f, 0.f, 0.f};
    sacc[j][0] = z; sacc[j][1] = z;
    if (t < NKT) {
#pragma unroll
      for (int ks = 0; ks < 2; ++ks) {
        s16x8 kf = *(const s16x8*)(kb + ((size_t)bh * NPAD + t * 16 + c) * HD + ks * 32 + g * 8);
        sacc[j][0] = mfma16(qf[0][ks], kf, sacc[j][0]);
        sacc[j][1] = mfma16(qf[1][ks], kf, sacc[j][1]);
      }
    }
  }

  // --- scale + bias (fragment-ordered global, coalesced 8B/thread) + mask; row max ---
  const u16* bt = btf + (size_t)(h * 19 + qt) * 20 * 1024;
  float rmax[2][4];
#pragma unroll
  for (int mf = 0; mf < 2; ++mf)
#pragma unroll
    for (int r = 0; r < 4; ++r) rmax[mf][r] = -1e30f;
#pragma unroll
  for (int j = 0; j < 10; ++j) {
    int t = wv + 4 * j;
    if (t < NKT) {
      int kcol = t * 16 + c;
#pragma unroll
      for (int mf = 0; mf < 2; ++mf) {
        ushort4 bb = *(const ushort4*)(bt + (size_t)((j * 2 + mf) * 256 + tid) * 4);
        u16 bbr[4] = {bb.x, bb.y, bb.z, bb.w};
#pragma unroll
        for (int r = 0; r < 4; ++r) {
          int lrow = mf * 16 + g * 4 + r;
          float sv;
          if (q0 + lrow < NTOK && kcol < NTOK)
            sv = sacc[j][mf][r] * SCALE + b2f(bbr[r]);
          else
            sv = -1e30f;
          sacc[j][mf][r] = sv;
          rmax[mf][r] = fmaxf(rmax[mf][r], sv);
        }
      }
    }
  }
#pragma unroll
  for (int d = 1; d < 16; d <<= 1)
#pragma unroll
    for (int mf = 0; mf < 2; ++mf)
#pragma unroll
      for (int r = 0; r < 4; ++r)
        rmax[mf][r] = fmaxf(rmax[mf][r], __shfl_xor(rmax[mf][r], d));
  if (c == 0) {
#pragma unroll
    for (int mf = 0; mf < 2; ++mf)
#pragma unroll
      for (int r = 0; r < 4; ++r) redm[wv][mf * 16 + g * 4 + r] = rmax[mf][r];
  }
  __syncthreads();
  float fmx[2][4];
#pragma unroll
  for (int mf = 0; mf < 2; ++mf)
#pragma unroll
    for (int r = 0; r < 4; ++r) {
      int row = mf * 16 + g * 4 + r;
      fmx[mf][r] = fmaxf(fmaxf(redm[0][row], redm[1][row]), fmaxf(redm[2][row], redm[3][row]));
    }

  // --- exp -> P into SLAB (swizzled), row sums ---
  float rsum[2][4] = {};
#pragma unroll
  for (int j = 0; j < 10; ++j) {
    int t = wv + 4 * j;
    if (t < NKT) {
      int kcol = t * 16 + c;
#pragma unroll
      for (int mf = 0; mf < 2; ++mf)
#pragma unroll
        for (int r = 0; r < 4; ++r) {
          int lrow = mf * 16 + g * 4 + r;
          float p = exp2f((sacc[j][mf][r] - fmx[mf][r]) * LOG2E);
          rsum[mf][r] += p;
          SLAB[lrow * NPAD + (kcol ^ ((lrow & 3) << 3))] = f2b(p);
        }
    }
  }
#pragma unroll
  for (int d = 1; d < 16; d <<= 1)
#pragma unroll
    for (int mf = 0; mf < 2; ++mf)
#pragma unroll
      for (int r = 0; r < 4; ++r) rsum[mf][r] += __shfl_xor(rsum[mf][r], d);
  if (c == 0) {
#pragma unroll
    for (int mf = 0; mf < 2; ++mf)
#pragma unroll
      for (int r = 0; r < 4; ++r) reds[wv][mf * 16 + g * 4 + r] = rsum[mf][r];
  }
  __syncthreads();  // P written + sums available
  float fsm[2][4];
#pragma unroll
  for (int mf = 0; mf < 2; ++mf)
#pragma unroll
    for (int r = 0; r < 4; ++r) {
      int row = mf * 16 + g * 4 + r;
      fsm[mf][r] = (reds[0][row] + reds[1][row]) + (reds[2][row] + reds[3][row]);
    }

  // --- PV: wave wv owns d-cols [wv*16, wv*16+16) ---
  f32x4 oacc[2] = {};
  for (int ks = 0; ks < 19; ++ks) {
    int col = ks * 32 + g * 8;
    s16x8 pf0 = *(const s16x8*)&SLAB[c * NPAD + (col ^ ((c & 3) << 3))];
    s16x8 pf1 = *(const s16x8*)&SLAB[(16 + c) * NPAD + (col ^ ((c & 3) << 3))];
    s16x8 vf = *(const s16x8*)(vt + ((size_t)bh * HD + wv * 16 + c) * NPAD + col);
    oacc[0] = mfma16(pf0, vf, oacc[0]);
    oacc[1] = mfma16(pf1, vf, oacc[1]);
  }

  // --- normalize + hi/lo split write ---
#pragma unroll
  for (int mf = 0; mf < 2; ++mf) {
#pragma unroll
    for (int r = 0; r < 4; ++r) {
      int tok = q0 + mf * 16 + g * 4 + r;
      if (tok < NTOK) {
        float v = oacc[mf][r] / fsm[mf][r];
        size_t idx = ((size_t)b * NTOK + tok) * DIMC + h * HD + wv * 16 + c;
        u16 hi = f2b(v);
        aohi[idx] = hi;
        aolo[idx] = f2b(v - b2f(hi));
      }
    }
  }
}

// ---------- launch ----------
extern "C" void kernel_launch(void* const* d_in, const int* in_sizes, int n_in,
                              void* d_out, int out_size, void* d_ws, size_t ws_size,
                              hipStream_t stream) {
  const float* x      = (const float*)d_in[0];
  const float* qkv_w  = (const float*)d_in[1];
  const float* btab   = (const float*)d_in[2];
  const float* proj_w = (const float*)d_in[3];
  const float* proj_b = (const float*)d_in[4];
  const int*   rel    = (const int*)d_in[5];
  float* out = (float*)d_out;

  char* ws = (char*)d_ws;
  size_t off = 0;
  auto alloc = [&](size_t bytes) {
    void* p = ws + off;
    off += (bytes + 255) & ~(size_t)255;
    return p;
  };
  constexpr size_t SZ_QKVB = (size_t)BATCH * NH * NPAD * HD * 2;
  u16* qb = (u16*)alloc(SZ_QKVB);
  u16* kb = (u16*)alloc(SZ_QKVB);
  u16* vt = (u16*)alloc(SZ_QKVB);
  u16* btf = (u16*)alloc((size_t)NH * 19 * 10 * 2 * 256 * 4 * 2);  // 9.34 MB frag-ordered bias
  u16* wth = (u16*)alloc((size_t)NQKV * DIMC * 2);
  u16* wtl = (u16*)alloc((size_t)NQKV * DIMC * 2);
  u16* w2h = (u16*)alloc((size_t)DIMC * DIMC * 2);
  u16* w2l = (u16*)alloc((size_t)DIMC * DIMC * 2);
  u16* xhi = (u16*)alloc((size_t)MROWS * DIMC * 2);
  u16* xlo = (u16*)alloc((size_t)MROWS * DIMC * 2);
  u16* aohi = xhi;  // x-split dead after QKV GEMM -> reuse
  u16* aolo = xlo;

  dim3 blk(256);
  {
    int n4 = MROWS * DIMC / 4;
    split_plain<<<(n4 + 255) / 256, blk, 0, stream>>>((const float4*)x, (ushort4*)xhi, (ushort4*)xlo, n4);
  }
  {
    int n = DIMC * NQKV;
    split_transpose<<<(n + 255) / 256, blk, 0, stream>>>(qkv_w, wth, wtl, DIMC, NQKV);
  }
  {
    int n = DIMC * DIMC;
    split_transpose<<<(n + 255) / 256, blk, 0, stream>>>(proj_w, w2h, w2l, DIMC, DIMC);
  }
  {
    int n = NH * 19 * 10 * 2 * 256;
    bias_expand_frag<<<(n + 255) / 256, blk, 0, stream>>>(btab, rel, btf);
  }
  {
    int mt = (MROWS + 127) / 128;  // 145
    int nt = NQKV / 128;           // 18
    gemm_split3<1><<<mt * nt, blk, 0, stream>>>(xhi, xlo, wth, wtl, MROWS, NQKV, DIMC, nt,
                                                nullptr, nullptr, qb, kb, vt);
  }
  attn_kernel<<<BATCH * NH * 19, blk, 0, stream>>>(qb, kb, vt, btf, aohi, aolo);
  {
    int mt = (MROWS + 127) / 128;  // 145
    int nt = DIMC / 128;           // 6
    gemm_split3<0><<<mt * nt, blk, 0, stream>>>(aohi, aolo, w2h, w2l, MROWS, DIMC, DIMC, nt,
                                                out, proj_b, nullptr, nullptr, nullptr);
  }
}

// Round 10
// 661.398 us; speedup vs baseline: 1.6234x; 1.0824x over previous
//
#include <hip/hip_runtime.h>

#define DEVI static __device__ __forceinline__

typedef short s16x8 __attribute__((ext_vector_type(8)));
typedef float f32x4 __attribute__((ext_vector_type(4)));
typedef unsigned short u16;

constexpr int BATCH = 32;
constexpr int NTOK  = 577;
constexpr int DIMC  = 768;
constexpr int NH    = 12;
constexpr int HD    = 64;
constexpr int NQKV  = 3 * DIMC;        // 2304
constexpr int MROWS = BATCH * NTOK;    // 18464
constexpr int NPAD  = 608;             // 19*32 padded token count
constexpr int NKT   = 38;              // 16-wide col tiles covering 608
constexpr int TSTR  = 2216;            // table slice stride (2210 padded to 16B mult)
constexpr float SCALE = 0.125f;        // 64^-0.5
constexpr float LOG2E = 1.44269504088896f;

// ---------- bf16 helpers (RNE) ----------
DEVI u16 f2b(float x) {
  unsigned u = __float_as_uint(x);
  u += 0x7fffu + ((u >> 16) & 1u);
  return (u16)(u >> 16);
}
DEVI float b2f(u16 h) { return __uint_as_float((unsigned)h << 16); }

DEVI void async16(void* lds, const void* g) {
  __builtin_amdgcn_global_load_lds((const __attribute__((address_space(1))) void*)g,
                                   (__attribute__((address_space(3))) void*)lds,
                                   16, 0, 0);
}
DEVI f32x4 mfma16(s16x8 a, s16x8 b, f32x4 c) {
  return __builtin_amdgcn_mfma_f32_16x16x32_bf16(a, b, c, 0, 0, 0);
}

// ---------- prep kernels ----------
__global__ __launch_bounds__(256) void split_plain(const float4* __restrict__ in,
                                                   ushort4* __restrict__ hi,
                                                   ushort4* __restrict__ lo, int n4) {
  int t = blockIdx.x * 256 + threadIdx.x;
  if (t >= n4) return;
  float4 v = in[t];
  ushort4 H, L;
  H.x = f2b(v.x); L.x = f2b(v.x - b2f(H.x));
  H.y = f2b(v.y); L.y = f2b(v.y - b2f(H.y));
  H.z = f2b(v.z); L.z = f2b(v.z - b2f(H.z));
  H.w = f2b(v.w); L.w = f2b(v.w - b2f(H.w));
  hi[t] = H; lo[t] = L;
}

__global__ __launch_bounds__(256) void split_transpose(const float* __restrict__ w,
                                                       u16* __restrict__ thi,
                                                       u16* __restrict__ tlo,
                                                       int K, int Nc) {
  int t = blockIdx.x * 256 + threadIdx.x;
  if (t >= K * Nc) return;
  int n = t / K, k = t - n * K;
  float v = w[(size_t)k * Nc + n];
  u16 h = f2b(v);
  thi[t] = h;
  tlo[t] = f2b(v - b2f(h));
}

// bias_table [2210][12] -> tabT [12][2216] bf16 (head-slice contiguous)
__global__ __launch_bounds__(256) void table_transpose(const float* __restrict__ tab,
                                                       u16* __restrict__ tabT) {
  int t = blockIdx.x * 256 + threadIdx.x;
  if (t >= NH * TSTR) return;
  int h = t / TSTR, i = t - h * TSTR;
  tabT[t] = (i < 2210) ? f2b(tab[(size_t)i * NH + h]) : (u16)0;
}

// ---------- fused 3-term split-bf16 GEMM, 2-phase double-buffered ----------
template <int MODE>
__global__ __launch_bounds__(256, 2) void gemm_split3(
    const u16* __restrict__ Ahi, const u16* __restrict__ Alo,
    const u16* __restrict__ Bhi, const u16* __restrict__ Blo,
    int M, int Nn, int K, int ntn,
    float* __restrict__ outF, const float* __restrict__ pbias,
    u16* __restrict__ qb, u16* __restrict__ kb, u16* __restrict__ vt) {
  __shared__ __align__(16) u16 Ah[2][128 * 32];
  __shared__ __align__(16) u16 Al[2][128 * 32];
  __shared__ __align__(16) u16 Bh[2][128 * 32];
  __shared__ __align__(16) u16 Bl[2][128 * 32];
  const int tid = threadIdx.x;
  const int lane = tid & 63, wv = tid >> 6;
  const int g = lane >> 4, c = lane & 15;

  // bijective XCD swizzle (m204)
  const int nwg = gridDim.x, bid = blockIdx.x;
  const int qq = nwg >> 3, rr8 = nwg & 7, xc = bid & 7, ii = bid >> 3;
  const int swz = (xc < rr8 ? xc * (qq + 1) : rr8 * (qq + 1) + (xc - rr8) * qq) + ii;
  const int mt = swz / ntn, ntb = swz % ntn;
  const int m0 = mt * 128, n0 = ntb * 128;
  const int wr = wv >> 1, wc = wv & 1;

  f32x4 acc[4][4] = {};

  const int ch0 = tid, ch1 = 256 + tid;
  const int r0 = ch0 >> 2, gk0 = (((ch0 & 3) ^ ((r0 >> 1) & 3)) * 8);
  const int r1 = ch1 >> 2, gk1 = (((ch1 & 3) ^ ((r1 >> 1) & 3)) * 8);
  const int ar0 = (m0 + r0 < M) ? (m0 + r0) : (M - 1);
  const int ar1 = (m0 + r1 < M) ? (m0 + r1) : (M - 1);
  const int br0 = n0 + r0, br1 = n0 + r1;

  const u16* ah0 = Ahi + (size_t)ar0 * K + gk0;
  const u16* ah1 = Ahi + (size_t)ar1 * K + gk1;
  const u16* al0 = Alo + (size_t)ar0 * K + gk0;
  const u16* al1 = Alo + (size_t)ar1 * K + gk1;
  const u16* bh0 = Bhi + (size_t)br0 * K + gk0;
  const u16* bh1 = Bhi + (size_t)br1 * K + gk1;
  const u16* bl0 = Blo + (size_t)br0 * K + gk0;
  const u16* bl1 = Blo + (size_t)br1 * K + gk1;

  auto STAGE = [&](int buf, int kk) {
    async16(&Ah[buf][ch0 * 8], ah0 + kk);
    async16(&Ah[buf][ch1 * 8], ah1 + kk);
    async16(&Al[buf][ch0 * 8], al0 + kk);
    async16(&Al[buf][ch1 * 8], al1 + kk);
    async16(&Bh[buf][ch0 * 8], bh0 + kk);
    async16(&Bh[buf][ch1 * 8], bh1 + kk);
    async16(&Bl[buf][ch0 * 8], bl0 + kk);
    async16(&Bl[buf][ch1 * 8], bl1 + kk);
  };
  auto COMPUTE = [&](int buf) {
    s16x8 afh[4], afl[4];
#pragma unroll
    for (int mi = 0; mi < 4; ++mi) {
      int row = wr * 64 + mi * 16 + c;
      int sl = g ^ ((row >> 1) & 3);
      afh[mi] = *(const s16x8*)&Ah[buf][row * 32 + sl * 8];
      afl[mi] = *(const s16x8*)&Al[buf][row * 32 + sl * 8];
    }
#pragma unroll
    for (int ni = 0; ni < 4; ++ni) {
      int row = wc * 64 + ni * 16 + c;
      int sl = g ^ ((row >> 1) & 3);
      s16x8 bfh = *(const s16x8*)&Bh[buf][row * 32 + sl * 8];
      s16x8 bfl = *(const s16x8*)&Bl[buf][row * 32 + sl * 8];
#pragma unroll
      for (int mi = 0; mi < 4; ++mi) {
        f32x4 t0 = mfma16(afh[mi], bfl, acc[mi][ni]);
        t0 = mfma16(afl[mi], bfh, t0);
        acc[mi][ni] = mfma16(afh[mi], bfh, t0);
      }
    }
  };

  STAGE(0, 0);
  __syncthreads();
  for (int kk = 0; kk < K; kk += 64) {
    if (kk + 32 < K) STAGE(1, kk + 32);
    COMPUTE(0);
    __syncthreads();
    if (kk + 64 < K) STAGE(0, kk + 64);
    COMPUTE(1);
    __syncthreads();
  }

#pragma unroll
  for (int mi = 0; mi < 4; ++mi) {
#pragma unroll
    for (int ni = 0; ni < 4; ++ni) {
#pragma unroll
      for (int r = 0; r < 4; ++r) {
        int row = m0 + wr * 64 + mi * 16 + g * 4 + r;
        int col = n0 + wc * 64 + ni * 16 + c;
        if (row < M) {
          float v = acc[mi][ni][r];
          if constexpr (MODE == 0) {
            outF[(size_t)row * Nn + col] = v + pbias[col];
          } else {
            int b = row / NTOK, tok = row - b * NTOK;
            int s = col / DIMC, rrx = col - s * DIMC;
            int h = rrx >> 6, d = rrx & 63;
            size_t bh = (size_t)b * NH + h;
            if (s == 2) {
              vt[(bh * HD + d) * NPAD + tok] = f2b(v);  // V transposed
            } else {
              u16* dst = (s == 0) ? qb : kb;
              dst[(bh * NPAD + tok) * HD + d] = f2b(v);
            }
          }
        }
      }
    }
  }
}

// ---------- attention ----------
// Bias computed in-kernel from 4.4KB head-slice table in LDS (aliased into SLAB).
// XCD swizzle co-locates the 19 q-tiles of each (b,h) -> K/V L2-resident.
// O written via LDS stage for full-cacheline coalesced stores.
__global__ __launch_bounds__(256) void attn_kernel(
    const u16* __restrict__ qb, const u16* __restrict__ kb, const u16* __restrict__ vt,
    const u16* __restrict__ tabT, u16* __restrict__ aohi, u16* __restrict__ aolo) {
  __shared__ __align__(16) u16 SLAB[32 * NPAD];   // 38912 B; aliases: bias table, P, O-stage
  __shared__ float redm[4][32];
  __shared__ float reds[4][32];
  const int tid = threadIdx.x, lane = tid & 63, wv = tid >> 6;
  const int g = lane >> 4, c = lane & 15;

  // XCD co-location: 7296 = 8 * 912
  const int work = (blockIdx.x & 7) * 912 + (blockIdx.x >> 3);
  const int qt = work % 19;
  const int bh = work / 19;
  const int h = bh % NH;
  const int b = bh / NH;
  const int q0 = qt * 32;

  // --- stage bias table slice (2216 u16 = 277 x 16B) into SLAB[0..2216) ---
  {
    const char* tsrc = (const char*)(tabT + (size_t)h * TSTR);
    for (int t = tid; t < 277; t += 256) async16(&SLAB[t * 8], tsrc + (size_t)t * 16);
  }

  // --- Q fragments ---
  s16x8 qf[2][2];
#pragma unroll
  for (int mf = 0; mf < 2; ++mf)
#pragma unroll
    for (int ks = 0; ks < 2; ++ks)
      qf[mf][ks] = *(const s16x8*)(qb + ((size_t)bh * NPAD + q0 + mf * 16 + c) * HD + ks * 32 + g * 8);

  // --- QK^T: wave wv owns tiles t = wv + 4j ---
  f32x4 sacc[10][2];
#pragma unroll
  for (int j = 0; j < 10; ++j) {
    int t = wv + 4 * j;
    f32x4 z = {0.f, 0.f, 0.f, 0.f};
    sacc[j][0] = z; sacc[j][1] = z;
    if (t < NKT) {
#pragma unroll
      for (int ks = 0; ks < 2; ++ks) {
        s16x8 kf = *(const s16x8*)(kb + ((size_t)bh * NPAD + t * 16 + c) * HD + ks * 32 + g * 8);
        sacc[j][0] = mfma16(qf[0][ks], kf, sacc[j][0]);
        sacc[j][1] = mfma16(qf[1][ks], kf, sacc[j][1]);
      }
    }
  }

  __syncthreads();  // table resident (barrier drains global_load_lds)

  // --- q-row geometry (8 rows per thread) ---
  int qrow[2][4], qh_[2][4], qw_[2][4];
#pragma unroll
  for (int mf = 0; mf < 2; ++mf)
#pragma unroll
    for (int r = 0; r < 4; ++r) {
      int q = q0 + mf * 16 + g * 4 + r;
      qrow[mf][r] = q;
      int qi = q - 1; if (qi < 0) qi = 0; if (qi > 575) qi = 575;
      qh_[mf][r] = qi / 24;
      qw_[mf][r] = qi - qh_[mf][r] * 24;
    }

  // --- scale + bias (LDS table gather) + mask; row max ---
  float rmax[2][4];
#pragma unroll
  for (int mf = 0; mf < 2; ++mf)
#pragma unroll
    for (int r = 0; r < 4; ++r) rmax[mf][r] = -1e30f;
#pragma unroll
  for (int j = 0; j < 10; ++j) {
    int t = wv + 4 * j;
    if (t < NKT) {
      int kcol = t * 16 + c;
      int ki = kcol - 1; if (ki < 0) ki = 0; if (ki > 575) ki = 575;
      int kh = ki / 24, kw = ki - kh * 24;
#pragma unroll
      for (int mf = 0; mf < 2; ++mf) {
#pragma unroll
        for (int r = 0; r < 4; ++r) {
          int idx = (qh_[mf][r] - kh + 23) * 47 + (qw_[mf][r] - kw + 23);
          if (qrow[mf][r] == 0 || kcol == 0) idx = 0;
          float bias = b2f(SLAB[idx]);
          float sv;
          if (qrow[mf][r] < NTOK && kcol < NTOK)
            sv = sacc[j][mf][r] * SCALE + bias;
          else
            sv = -1e30f;
          sacc[j][mf][r] = sv;
          rmax[mf][r] = fmaxf(rmax[mf][r], sv);
        }
      }
    }
  }
#pragma unroll
  for (int d = 1; d < 16; d <<= 1)
#pragma unroll
    for (int mf = 0; mf < 2; ++mf)
#pragma unroll
      for (int r = 0; r < 4; ++r)
        rmax[mf][r] = fmaxf(rmax[mf][r], __shfl_xor(rmax[mf][r], d));
  if (c == 0) {
#pragma unroll
    for (int mf = 0; mf < 2; ++mf)
#pragma unroll
      for (int r = 0; r < 4; ++r) redm[wv][mf * 16 + g * 4 + r] = rmax[mf][r];
  }
  __syncthreads();  // all bias reads done; safe to overwrite SLAB with P
  float fmx[2][4];
#pragma unroll
  for (int mf = 0; mf < 2; ++mf)
#pragma unroll
    for (int r = 0; r < 4; ++r) {
      int row = mf * 16 + g * 4 + r;
      fmx[mf][r] = fmaxf(fmaxf(redm[0][row], redm[1][row]), fmaxf(redm[2][row], redm[3][row]));
    }

  // --- exp -> P into SLAB (swizzled), row sums ---
  float rsum[2][4] = {};
#pragma unroll
  for (int j = 0; j < 10; ++j) {
    int t = wv + 4 * j;
    if (t < NKT) {
      int kcol = t * 16 + c;
#pragma unroll
      for (int mf = 0; mf < 2; ++mf)
#pragma unroll
        for (int r = 0; r < 4; ++r) {
          int lrow = mf * 16 + g * 4 + r;
          float p = exp2f((sacc[j][mf][r] - fmx[mf][r]) * LOG2E);
          rsum[mf][r] += p;
          SLAB[lrow * NPAD + (kcol ^ ((lrow & 3) << 3))] = f2b(p);
        }
    }
  }
#pragma unroll
  for (int d = 1; d < 16; d <<= 1)
#pragma unroll
    for (int mf = 0; mf < 2; ++mf)
#pragma unroll
      for (int r = 0; r < 4; ++r) rsum[mf][r] += __shfl_xor(rsum[mf][r], d);
  if (c == 0) {
#pragma unroll
    for (int mf = 0; mf < 2; ++mf)
#pragma unroll
      for (int r = 0; r < 4; ++r) reds[wv][mf * 16 + g * 4 + r] = rsum[mf][r];
  }
  __syncthreads();  // P written + sums available
  float fsm[2][4];
#pragma unroll
  for (int mf = 0; mf < 2; ++mf)
#pragma unroll
    for (int r = 0; r < 4; ++r) {
      int row = mf * 16 + g * 4 + r;
      fsm[mf][r] = (reds[0][row] + reds[1][row]) + (reds[2][row] + reds[3][row]);
    }

  // --- PV: wave wv owns d-cols [wv*16, wv*16+16) ---
  f32x4 oacc[2] = {};
  for (int ks = 0; ks < 19; ++ks) {
    int col = ks * 32 + g * 8;
    s16x8 pf0 = *(const s16x8*)&SLAB[c * NPAD + (col ^ ((c & 3) << 3))];
    s16x8 pf1 = *(const s16x8*)&SLAB[(16 + c) * NPAD + (col ^ ((c & 3) << 3))];
    s16x8 vf = *(const s16x8*)(vt + ((size_t)bh * HD + wv * 16 + c) * NPAD + col);
    oacc[0] = mfma16(pf0, vf, oacc[0]);
    oacc[1] = mfma16(pf1, vf, oacc[1]);
  }

  __syncthreads();  // all P reads done; reuse SLAB for O staging

  // --- normalize + hi/lo into LDS (stride 68 spreads g across banks) ---
#pragma unroll
  for (int mf = 0; mf < 2; ++mf) {
#pragma unroll
    for (int r = 0; r < 4; ++r) {
      int tokl = mf * 16 + g * 4 + r;
      int d = wv * 16 + c;
      float v = oacc[mf][r] / fsm[mf][r];
      u16 hi = f2b(v);
      SLAB[tokl * 68 + d] = hi;
      SLAB[2176 + tokl * 68 + d] = f2b(v - b2f(hi));
    }
  }
  __syncthreads();

  // --- coalesced copy-out: 32 rows x 128B per array, full cachelines ---
  {
    int row = tid >> 3, seg = tid & 7;
    int tok = q0 + row;
    if (tok < NTOK) {
      size_t base = ((size_t)b * NTOK + tok) * DIMC + h * HD + seg * 8;
      u16 vh[8], vl[8];
#pragma unroll
      for (int e = 0; e < 8; ++e) {
        vh[e] = SLAB[row * 68 + seg * 8 + e];
        vl[e] = SLAB[2176 + row * 68 + seg * 8 + e];
      }
      *(s16x8*)(aohi + base) = *(s16x8*)vh;
      *(s16x8*)(aolo + base) = *(s16x8*)vl;
    }
  }
}

// ---------- launch ----------
extern "C" void kernel_launch(void* const* d_in, const int* in_sizes, int n_in,
                              void* d_out, int out_size, void* d_ws, size_t ws_size,
                              hipStream_t stream) {
  const float* x      = (const float*)d_in[0];
  const float* qkv_w  = (const float*)d_in[1];
  const float* btab   = (const float*)d_in[2];
  const float* proj_w = (const float*)d_in[3];
  const float* proj_b = (const float*)d_in[4];
  const int*   rel    = (const int*)d_in[5];
  (void)rel;
  float* out = (float*)d_out;

  char* ws = (char*)d_ws;
  size_t off = 0;
  auto alloc = [&](size_t bytes) {
    void* p = ws + off;
    off += (bytes + 255) & ~(size_t)255;
    return p;
  };
  constexpr size_t SZ_QKVB = (size_t)BATCH * NH * NPAD * HD * 2;
  u16* qb = (u16*)alloc(SZ_QKVB);
  u16* kb = (u16*)alloc(SZ_QKVB);
  u16* vt = (u16*)alloc(SZ_QKVB);
  u16* tabT = (u16*)alloc((size_t)NH * TSTR * 2);   // 53 KB head-major bias table
  u16* wth = (u16*)alloc((size_t)NQKV * DIMC * 2);
  u16* wtl = (u16*)alloc((size_t)NQKV * DIMC * 2);
  u16* w2h = (u16*)alloc((size_t)DIMC * DIMC * 2);
  u16* w2l = (u16*)alloc((size_t)DIMC * DIMC * 2);
  u16* xhi = (u16*)alloc((size_t)MROWS * DIMC * 2);
  u16* xlo = (u16*)alloc((size_t)MROWS * DIMC * 2);
  u16* aohi = xhi;  // x-split dead after QKV GEMM -> reuse
  u16* aolo = xlo;

  dim3 blk(256);
  {
    int n4 = MROWS * DIMC / 4;
    split_plain<<<(n4 + 255) / 256, blk, 0, stream>>>((const float4*)x, (ushort4*)xhi, (ushort4*)xlo, n4);
  }
  {
    int n = DIMC * NQKV;
    split_transpose<<<(n + 255) / 256, blk, 0, stream>>>(qkv_w, wth, wtl, DIMC, NQKV);
  }
  {
    int n = DIMC * DIMC;
    split_transpose<<<(n + 255) / 256, blk, 0, stream>>>(proj_w, w2h, w2l, DIMC, DIMC);
  }
  {
    int n = NH * TSTR;
    table_transpose<<<(n + 255) / 256, blk, 0, stream>>>(btab, tabT);
  }
  {
    int mt = (MROWS + 127) / 128;  // 145
    int nt = NQKV / 128;           // 18
    gemm_split3<1><<<mt * nt, blk, 0, stream>>>(xhi, xlo, wth, wtl, MROWS, NQKV, DIMC, nt,
                                                nullptr, nullptr, qb, kb, vt);
  }
  attn_kernel<<<BATCH * NH * 19, blk, 0, stream>>>(qb, kb, vt, tabT, aohi, aolo);
  {
    int mt = (MROWS + 127) / 128;  // 145
    int nt = DIMC / 128;           // 6
    gemm_split3<0><<<mt * nt, blk, 0, stream>>>(aohi, aolo, w2h, w2l, MROWS, DIMC, DIMC, nt,
                                                out, proj_b, nullptr, nullptr, nullptr);
  }
}